// Round 1
// baseline (1170.869 us; speedup 1.0000x reference)
//
#include <hip/hip_runtime.h>
#include <stdint.h>

#define B    4096
#define NU   20000
#define NI   10000
#define RS   10001   // interactions row stride (ints)
#define SU   16      // split-K segments, user pass
#define SI   16      // split-K segments, item pass
#define CHU  157     // ceil(10000/64)
#define CHI  313     // ceil(20000/64)

// ---------- K0: transpose (64 x N) -> (N x 64) ----------
__global__ void k_transpose(const float* __restrict__ in, float* __restrict__ out, int N) {
  __shared__ float t[64][65];
  int tx = threadIdx.x & 63, ty = threadIdx.x >> 6;
  int j0 = blockIdx.x * 64;
  for (int r = ty; r < 64; r += 4) {
    int j = j0 + tx;
    t[r][tx] = (j < N) ? in[(size_t)r * N + j] : 0.f;
  }
  __syncthreads();
  for (int r = ty; r < 64; r += 4) {
    int n = j0 + r;
    if (n < N) out[(size_t)n * 64 + tx] = t[tx][r];
  }
}

// ---------- K1: bit-pack needed columns: G[u][w] bit l = X[u][item_idx[w*64+l]] ----------
__global__ void k_bitpack(const int* __restrict__ X, const int* __restrict__ item_idx,
                          unsigned long long* __restrict__ G) {
  __shared__ int row[NI];
  int u = blockIdx.x;
  const int* xr = X + (size_t)u * RS;
  for (int j = threadIdx.x; j < NI; j += 256) row[j] = xr[j];
  __syncthreads();
  int lane = threadIdx.x & 63, w = threadIdx.x >> 6;
  for (int wq = w; wq < 64; wq += 4) {
    int c = item_idx[wq * 64 + lane];
    unsigned long long m = __ballot(row[c] != 0);
    if (lane == 0) G[(size_t)u * 64 + wq] = m;
  }
}

// ---------- K2: user-path partial sums (64 b's per block, split-K) ----------
__global__ __launch_bounds__(256) void k_user(const int* __restrict__ X,
    const int* __restrict__ user_idx, const float* __restrict__ WuT,
    float* __restrict__ partF, int* __restrict__ partC) {
  __shared__ float wt[64][64];
  __shared__ int su[64];
  int lane = threadIdx.x & 63, w = threadIdx.x >> 6;
  int bg = blockIdx.x, seg = blockIdx.y;
  int b0 = bg * 64;
  if (threadIdx.x < 64) su[threadIdx.x] = user_idx[b0 + threadIdx.x];
  __syncthreads();
  float acc[16];
#pragma unroll
  for (int i = 0; i < 16; i++) acc[i] = 0.f;
  int cnt = 0;
  for (int kc = seg; kc < CHU; kc += SU) {
    int j0 = kc * 64;
    int jn = min(64, NI - j0);
    for (int r = w; r < 64; r += 4)
      wt[r][lane] = (r < jn) ? WuT[(size_t)(j0 + r) * 64 + lane] : 0.f;
    __syncthreads();
    int xv = (lane < jn) ? X[(size_t)su[w * 16] * RS + j0 + lane] : 0;
#pragma unroll
    for (int i = 0; i < 16; i++) {
      unsigned long long m = __ballot(xv != 0);
      if (i < 15)
        xv = (lane < jn) ? X[(size_t)su[w * 16 + i + 1] * RS + j0 + lane] : 0;
      cnt += (lane == i) ? __popcll(m) : 0;
      while (m) {
        int jl = __builtin_ctzll(m);
        m &= m - 1;
        acc[i] += wt[jl][lane];
      }
    }
    __syncthreads();
  }
#pragma unroll
  for (int i = 0; i < 16; i++) {
    int b = b0 + w * 16 + i;
    partF[((size_t)seg * B + b) * 64 + lane] = acc[i];
  }
  if (lane < 16) partC[seg * B + b0 + w * 16 + lane] = cnt;
}

// ---------- K3: item-path partial sums (reads bit-matrix G) ----------
__global__ __launch_bounds__(256) void k_item(const unsigned long long* __restrict__ G,
    const float* __restrict__ WiT, float* __restrict__ partF, int* __restrict__ partC) {
  __shared__ float wt[64][64];
  int lane = threadIdx.x & 63, w = threadIdx.x >> 6;
  int bg = blockIdx.x, seg = blockIdx.y;
  int b0 = bg * 64;
  float acc[16];
#pragma unroll
  for (int i = 0; i < 16; i++) acc[i] = 0.f;
  int cnt = 0;
  for (int kc = seg; kc < CHI; kc += SI) {
    int u0 = kc * 64;
    int un = min(64, NU - u0);
    for (int r = w; r < 64; r += 4)
      wt[r][lane] = (r < un) ? WiT[(size_t)(u0 + r) * 64 + lane] : 0.f;
    __syncthreads();
    unsigned long long gw = (lane < un) ? G[(size_t)(u0 + lane) * 64 + bg] : 0ULL;
#pragma unroll
    for (int i = 0; i < 16; i++) {
      int mb = w * 16 + i;
      unsigned long long m = __ballot((int)((gw >> mb) & 1ULL));
      cnt += (lane == i) ? __popcll(m) : 0;
      while (m) {
        int ul = __builtin_ctzll(m);
        m &= m - 1;
        acc[i] += wt[ul][lane];
      }
    }
    __syncthreads();
  }
#pragma unroll
  for (int i = 0; i < 16; i++) {
    int b = b0 + w * 16 + i;
    partF[((size_t)seg * B + b) * 64 + lane] = acc[i];
  }
  if (lane < 16) partC[seg * B + b0 + w * 16 + lane] = cnt;
}

// ---------- R: reduce split-K partials + mask-fix + normalize + embed add ----------
// mode 0 (user): subtract WmT[item_idx[b]], embed row = user_idx[b]
// mode 1 (item): subtract WmT[user_idx[b]], embed row = item_idx[b]
__global__ void k_reduce(const float* __restrict__ partF, const int* __restrict__ partC,
    int S, const int* __restrict__ user_idx, const int* __restrict__ item_idx,
    const int* __restrict__ X, const float* __restrict__ WmT,
    const float* __restrict__ embed, int mode, float* __restrict__ rep) {
  int gid = blockIdx.x * 256 + threadIdx.x;
  int b = gid >> 6, f = gid & 63;
  float a = 0.f;
  int cnt = 0;
  for (int s = 0; s < S; s++) {
    a += partF[((size_t)s * B + b) * 64 + f];
    cnt += partC[s * B + b];
  }
  int u = user_idx[b], c = item_idx[b];
  int xc = X[(size_t)u * RS + c];
  int mrow = mode ? u : c;
  if (xc) { a -= WmT[(size_t)mrow * 64 + f]; cnt -= 1; }
  float denom = (float)cnt;
  if (denom < 1.f) denom = 1.f;
  float hist = a / sqrtf(denom);
  int erow = mode ? c : u;
  rep[(size_t)b * 64 + f] = embed[(size_t)erow * 64 + f] + hist;
}

// ---------- K4: GMF dot + bias ----------
__global__ void k_logit(const float* __restrict__ ru, const float* __restrict__ ri,
    const float* __restrict__ lw, const float* __restrict__ lb, float* __restrict__ out) {
  int lane = threadIdx.x & 63, w = threadIdx.x >> 6;
  int b = blockIdx.x * 4 + w;
  float v = ru[(size_t)b * 64 + lane] * ri[(size_t)b * 64 + lane] * lw[lane];
  for (int off = 32; off; off >>= 1) v += __shfl_xor(v, off);
  if (lane == 0) out[b] = v + lb[0];
}

extern "C" void kernel_launch(void* const* d_in, const int* in_sizes, int n_in,
                              void* d_out, int out_size, void* d_ws, size_t ws_size,
                              hipStream_t stream) {
  const int*   user_idx = (const int*)d_in[0];
  const int*   item_idx = (const int*)d_in[1];
  const int*   X        = (const int*)d_in[2];
  const float* uew      = (const float*)d_in[3];
  const float* iew      = (const float*)d_in[4];
  const float* pu       = (const float*)d_in[5];
  const float* pi       = (const float*)d_in[6];
  const float* lw       = (const float*)d_in[7];
  const float* lb       = (const float*)d_in[8];
  float* out = (float*)d_out;

  char* wsb = (char*)d_ws;
  float* WuT                 = (float*)(wsb + 0);          //  2,560,000 B
  float* WiT                 = (float*)(wsb + 2560000);    //  5,120,000 B
  unsigned long long* G      = (unsigned long long*)(wsb + 7680000);   // 10,240,000 B
  float* partF               = (float*)(wsb + 17920000);   // 16,777,216 B
  int*   partC               = (int*)  (wsb + 34697216);   //    262,144 B
  float* rep_u               = (float*)(wsb + 34959360);   //  1,048,576 B
  float* rep_i               = (float*)(wsb + 36007936);   //  1,048,576 B

  k_transpose<<<157, 256, 0, stream>>>(pu, WuT, NI);
  k_transpose<<<313, 256, 0, stream>>>(pi, WiT, NU);
  k_bitpack<<<NU, 256, 0, stream>>>(X, item_idx, G);
  k_user<<<dim3(64, SU), 256, 0, stream>>>(X, user_idx, WuT, partF, partC);
  k_reduce<<<1024, 256, 0, stream>>>(partF, partC, SU, user_idx, item_idx, X, WuT, uew, 0, rep_u);
  k_item<<<dim3(64, SI), 256, 0, stream>>>(G, WiT, partF, partC);
  k_reduce<<<1024, 256, 0, stream>>>(partF, partC, SI, user_idx, item_idx, X, WiT, iew, 1, rep_i);
  k_logit<<<1024, 256, 0, stream>>>(rep_u, rep_i, lw, lb, out);
}

// Round 2
// 399.436 us; speedup vs baseline: 2.9313x; 2.9313x over previous
//
#include <hip/hip_runtime.h>
#include <hip/hip_bf16.h>
#include <stdint.h>

#define B    4096
#define NU   20000
#define NI   10000
#define RS   10001   // interactions row stride (ints)
#define SPK  8       // split-K segments
#define GBS  625     // Gb row stride in dwords (20000 bits exactly)
#define XUS  320     // Xu row stride in dwords (313 used, bits 10000..10015 zero)

typedef __attribute__((ext_vector_type(8))) short bf16x8;
typedef __attribute__((ext_vector_type(4))) float f32x4;

// ---------- K1: bit-pack needed columns: G[u][w] bit l = X[u][item_idx[w*64+l]] ----------
__global__ void k_bitpack(const int* __restrict__ X, const int* __restrict__ item_idx,
                          unsigned long long* __restrict__ G) {
  __shared__ int row[NI];
  int u = blockIdx.x;
  const int* xr = X + (size_t)u * RS;
  for (int j = threadIdx.x; j < NI; j += 256) row[j] = xr[j];
  __syncthreads();
  int lane = threadIdx.x & 63, w = threadIdx.x >> 6;
  for (int wq = w; wq < 64; wq += 4) {
    int c = item_idx[wq * 64 + lane];
    unsigned long long m = __ballot(row[c] != 0);
    if (lane == 0) G[(size_t)u * 64 + wq] = m;
  }
}

// ---------- K2: 64x64 bit-block transpose: G (u-major over b) -> Gb (b-major over u) ----------
__global__ void k_transG(const unsigned long long* __restrict__ G, uint32_t* __restrict__ Gb) {
  int lane = threadIdx.x & 63, w = threadIdx.x >> 6;
  int uc = blockIdx.x, wfull = blockIdx.y * 4 + w;
  int u = uc * 64 + lane;
  unsigned long long g = (u < NU) ? G[(size_t)u * 64 + wfull] : 0ULL;
  unsigned long long mym = 0;
#pragma unroll 8
  for (int j = 0; j < 64; j++) {
    unsigned long long mm = __ballot((int)((g >> j) & 1ULL));
    if (lane == j) mym = mm;
  }
  int b = wfull * 64 + lane;
  Gb[(size_t)b * GBS + uc * 2] = (uint32_t)mym;
  if (uc * 2 + 1 < GBS) Gb[(size_t)b * GBS + uc * 2 + 1] = (uint32_t)(mym >> 32);
}

// ---------- K3: gather+pack user rows: Xu[b] bits j = X[user_idx[b]][j] ----------
__global__ void k_packU(const int* __restrict__ X, const int* __restrict__ user_idx,
                        unsigned long long* __restrict__ Xu) {
  int b = blockIdx.x;
  const int* row = X + (size_t)user_idx[b] * RS;
  int lane = threadIdx.x & 63;
  for (int j = threadIdx.x; j < 10048; j += 256) {
    int v = (j < NI) ? row[j] : 0;
    unsigned long long m = __ballot(v != 0);
    if (lane == 0) Xu[(size_t)b * (XUS / 2) + (j >> 6)] = m;
  }
}

// ---------- K4: weight -> per-lane-contiguous bf16 fragment stream ----------
// slot (ks,t,lane,j): W[u = ks*32 + (lane>>4)*8 + j][f = t*16 + (lane&15)], src is (64 x NSRC) f32
__global__ void k_prepW(const float* __restrict__ src, int NSRC, int nk,
                        uint4* __restrict__ wfrag) {
  int idx = blockIdx.x * 256 + threadIdx.x;  // (ks*4 + t)*64 + l
  int l = idx & 63, t = (idx >> 6) & 3, ks = idx >> 8;
  if (ks >= nk) return;
  int g = l >> 4, f = t * 16 + (l & 15);
  int u0 = ks * 32 + g * 8;
  uint32_t w[4];
#pragma unroll
  for (int p = 0; p < 4; p++) {
    float lo = (u0 + 2 * p     < NSRC) ? src[(size_t)f * NSRC + u0 + 2 * p]     : 0.f;
    float hi = (u0 + 2 * p + 1 < NSRC) ? src[(size_t)f * NSRC + u0 + 2 * p + 1] : 0.f;
    __hip_bfloat16 blo = __float2bfloat16(lo), bhi = __float2bfloat16(hi);
    w[p] = (uint32_t)*(uint16_t*)&blo | ((uint32_t)*(uint16_t*)&bhi << 16);
  }
  wfrag[idx] = make_uint4(w[0], w[1], w[2], w[3]);
}

// ---------- K5: MFMA GEMM: partF[seg][b][f] = sum_{k in seg} bit(b,k) * W[k][f] ----------
__global__ __launch_bounds__(256) void k_mfma(const uint32_t* __restrict__ bits, int bstride,
    const uint4* __restrict__ wfrag, int nk, float* __restrict__ partF) {
  int lane = threadIdx.x & 63, wid = threadIdx.x >> 6;
  int mtile = blockIdx.x * 4 + wid, seg = blockIdx.y;
  int b0 = mtile * 16;
  int row = b0 + (lane & 15), g = lane >> 4;
  f32x4 acc[4] = {{0,0,0,0},{0,0,0,0},{0,0,0,0},{0,0,0,0}};
  const uint32_t* brow = bits + (size_t)row * bstride;
  for (int ks = seg; ks < nk; ks += SPK) {
    uint32_t ab = brow[ks];
    uint32_t by = (ab >> (g * 8)) & 0xffu;
    union { bf16x8 v; uint32_t u[4]; } A;
#pragma unroll
    for (int p = 0; p < 4; p++) {
      uint32_t blo = (by >> (2 * p)) & 1u, bhi = (by >> (2 * p + 1)) & 1u;
      A.u[p] = (blo ? 0x3F80u : 0u) | (bhi ? 0x3F800000u : 0u);
    }
    const uint4* wp = wfrag + (size_t)ks * 256 + lane;
#pragma unroll
    for (int t = 0; t < 4; t++) {
      union { bf16x8 v; uint4 q; } Bf;
      Bf.q = wp[t * 64];
      acc[t] = __builtin_amdgcn_mfma_f32_16x16x32_bf16(A.v, Bf.v, acc[t], 0, 0, 0);
    }
  }
#pragma unroll
  for (int t = 0; t < 4; t++)
#pragma unroll
    for (int r = 0; r < 4; r++) {
      int b = b0 + (lane >> 4) * 4 + r;
      partF[((size_t)seg * B + b) * 64 + t * 16 + (lane & 15)] = acc[t][r];
    }
}

// ---------- K6: reduce split-K + popcount + mask-fix + normalize + embed add ----------
// mode 0 (user): mask row = item_idx[b] in src, embed row = user_idx[b]
// mode 1 (item): mask row = user_idx[b] in src, embed row = item_idx[b]
__global__ void k_reduceB(const float* __restrict__ partF,
    const uint32_t* __restrict__ bits, int bstride, int ndw,
    const int* __restrict__ user_idx, const int* __restrict__ item_idx,
    const int* __restrict__ X, const float* __restrict__ src, int NSRC,
    const float* __restrict__ embed, int mode, float* __restrict__ rep) {
  int gid = blockIdx.x * 256 + threadIdx.x;
  int b = gid >> 6, f = gid & 63;
  float a = 0.f;
  for (int s = 0; s < SPK; s++) a += partF[((size_t)s * B + b) * 64 + f];
  const uint32_t* rowp = bits + (size_t)b * bstride;
  int c = 0;
  for (int d = f; d < ndw; d += 64) c += __popc(rowp[d]);
  for (int off = 32; off; off >>= 1) c += __shfl_xor(c, off);
  int u = user_idx[b], it = item_idx[b];
  int xc = X[(size_t)u * RS + it];
  int mrow = mode ? u : it;
  if (xc) { a -= src[(size_t)f * NSRC + mrow]; c -= 1; }
  float denom = (float)c;
  if (denom < 1.f) denom = 1.f;
  int erow = mode ? it : u;
  rep[(size_t)b * 64 + f] = embed[(size_t)erow * 64 + f] + a / sqrtf(denom);
}

// ---------- K7: GMF dot + bias ----------
__global__ void k_logit(const float* __restrict__ ru, const float* __restrict__ ri,
    const float* __restrict__ lw, const float* __restrict__ lb, float* __restrict__ out) {
  int lane = threadIdx.x & 63, w = threadIdx.x >> 6;
  int b = blockIdx.x * 4 + w;
  float v = ru[(size_t)b * 64 + lane] * ri[(size_t)b * 64 + lane] * lw[lane];
  for (int off = 32; off; off >>= 1) v += __shfl_xor(v, off);
  if (lane == 0) out[b] = v + lb[0];
}

extern "C" void kernel_launch(void* const* d_in, const int* in_sizes, int n_in,
                              void* d_out, int out_size, void* d_ws, size_t ws_size,
                              hipStream_t stream) {
  const int*   user_idx = (const int*)d_in[0];
  const int*   item_idx = (const int*)d_in[1];
  const int*   X        = (const int*)d_in[2];
  const float* uew      = (const float*)d_in[3];
  const float* iew      = (const float*)d_in[4];
  const float* pu       = (const float*)d_in[5];   // (64, 10000)
  const float* pi       = (const float*)d_in[6];   // (64, 20000)
  const float* lw       = (const float*)d_in[7];
  const float* lb       = (const float*)d_in[8];
  float* out = (float*)d_out;

  char* wsb = (char*)d_ws;
  uint32_t*           Gb    = (uint32_t*)(wsb + 0);            // 10,240,000 B
  unsigned long long* G     = (unsigned long long*)(wsb + 10240000); // 10,240,000 B (dead after k_transG)
  float*              partF = (float*)(wsb + 10240000);        //  8,388,608 B (aliases G)
  float*              rep_u = (float*)(wsb + 20480000);        //  1,048,576 B
  float*              rep_i = (float*)(wsb + 21528576);        //  1,048,576 B
  unsigned long long* Xu    = (unsigned long long*)(wsb + 22577152); // 5,242,880 B
  uint4*              WfI   = (uint4*)(wsb + 27820032);        //  2,560,000 B
  uint4*              WfU   = (uint4*)(wsb + 30380032);        //  1,282,048 B

  k_prepW<<<625, 256, 0, stream>>>(pi, NU, 625, WfI);
  k_prepW<<<313, 256, 0, stream>>>(pu, NI, 313, WfU);
  k_bitpack<<<NU, 256, 0, stream>>>(X, item_idx, G);
  k_transG<<<dim3(313, 16), 256, 0, stream>>>(G, Gb);
  k_packU<<<B, 256, 0, stream>>>(X, user_idx, Xu);

  // item path: hist_i[b][f] = sum_u Gb(b,u) * pi[f][u]
  k_mfma<<<dim3(64, SPK), 256, 0, stream>>>(Gb, GBS, WfI, 625, partF);
  k_reduceB<<<1024, 256, 0, stream>>>(partF, Gb, GBS, 625,
      user_idx, item_idx, X, pi, NU, iew, 1, rep_i);

  // user path: hist_u[b][f] = sum_j Xu(b,j) * pu[f][j]
  k_mfma<<<dim3(64, SPK), 256, 0, stream>>>((const uint32_t*)Xu, XUS, WfU, 313, partF);
  k_reduceB<<<1024, 256, 0, stream>>>(partF, (const uint32_t*)Xu, XUS, 313,
      user_idx, item_idx, X, pu, NI, uew, 0, rep_u);

  k_logit<<<1024, 256, 0, stream>>>(rep_u, rep_i, lw, lb, out);
}